// Round 2
// baseline (18001.147 us; speedup 1.0000x reference)
//
#include <hip/hip_runtime.h>

typedef __bf16 bf16x8 __attribute__((ext_vector_type(8)));
typedef __bf16 bf16x2 __attribute__((ext_vector_type(2)));
typedef float f32x4 __attribute__((ext_vector_type(4)));

#define T_SEQ 256
#define BB 64
#define HH 512

__device__ __forceinline__ float sigmoidf_(float x) {
    return 1.f / (1.f + __expf(-x));
}
__device__ __forceinline__ float tanhf_(float x) {
    return 1.f - 2.f / (__expf(2.f * x) + 1.f);
}

// ---------------- gather embeddings -> bf16 [T][B][H] ----------------
__global__ void gather_emb(const int* __restrict__ tok, const float* __restrict__ emb,
                           __bf16* __restrict__ x, int T) {
    size_t e = (size_t)blockIdx.x * blockDim.x + threadIdx.x; // over T*64*512
    int h = (int)(e & 511);
    int b = (int)((e >> 9) & 63);
    int t = (int)(e >> 15);
    int tk = tok[b * T + t];
    x[e] = (__bf16)emb[(size_t)tk * 512 + h];
}

// ---------------- transpose+convert f32 [R][C] -> bf16 [C][R], batched in z ----
__global__ void transpose_w(const float* __restrict__ in, __bf16* __restrict__ out,
                            int R, int C) {
    __shared__ __bf16 tile[64][66];
    const size_t sl = (size_t)blockIdx.z * R * C;
    in += sl; out += sl;
    int c0 = blockIdx.x * 64, r0 = blockIdx.y * 64;
    int ci = threadIdx.x & 63, rb = threadIdx.x >> 6;
#pragma unroll
    for (int s = 0; s < 16; s++) {
        int ri = s * 4 + rb;
        tile[ri][ci] = (__bf16)in[(size_t)(r0 + ri) * C + c0 + ci];
    }
    __syncthreads();
#pragma unroll
    for (int s = 0; s < 16; s++) {
        int cc = s * 4 + rb;
        out[(size_t)(c0 + cc) * R + r0 + ci] = tile[ci][cc];
    }
}

// ---------------- bf16 MFMA GEMM: C[M,N](bf16) = A[M,K] @ Bt[N,K]^T ----------
__global__ __launch_bounds__(256) void gemm_bf16(const __bf16* __restrict__ A,
                                                 const __bf16* __restrict__ Bt,
                                                 __bf16* __restrict__ C,
                                                 int M, int N, int K) {
    __shared__ __align__(16) __bf16 As[128 * 32];
    __shared__ __align__(16) __bf16 Bs[128 * 32];
    const int tid = threadIdx.x;
    const int lane = tid & 63, w = tid >> 6;
    const int l15 = lane & 15, quad = lane >> 4;
    const int m0 = blockIdx.y * 128, n0 = blockIdx.x * 128;
    const int wm = (w >> 1) * 64, wn = (w & 1) * 64;
    f32x4 acc[4][4] = {};
    const int r = tid >> 1, seg = (tid & 1) * 16;
    const __bf16* Ag = A + (size_t)(m0 + r) * K + seg;
    const __bf16* Bg = Bt + (size_t)(n0 + r) * K + seg;
    for (int kb = 0; kb < K; kb += 32) {
        // each thread stages 16 bf16 = 32 bytes (two uint4 copies)
        *(uint4*)(&As[r * 32 + seg]) = *(const uint4*)(Ag + kb);
        *(uint4*)(&As[r * 32 + seg + 8]) = *(const uint4*)(Ag + kb + 8);
        *(uint4*)(&Bs[r * 32 + seg]) = *(const uint4*)(Bg + kb);
        *(uint4*)(&Bs[r * 32 + seg + 8]) = *(const uint4*)(Bg + kb + 8);
        __syncthreads();
        bf16x8 fa[4], fb[4];
#pragma unroll
        for (int i = 0; i < 4; i++)
            fa[i] = *(const bf16x8*)(&As[(wm + i * 16 + l15) * 32 + quad * 8]);
#pragma unroll
        for (int j = 0; j < 4; j++)
            fb[j] = *(const bf16x8*)(&Bs[(wn + j * 16 + l15) * 32 + quad * 8]);
#pragma unroll
        for (int i = 0; i < 4; i++)
#pragma unroll
            for (int j = 0; j < 4; j++)
                acc[i][j] = __builtin_amdgcn_mfma_f32_16x16x32_bf16(fa[i], fb[j], acc[i][j], 0, 0, 0);
        __syncthreads();
    }
#pragma unroll
    for (int i = 0; i < 4; i++) {
        int m = m0 + wm + i * 16 + quad * 4;
#pragma unroll
        for (int j = 0; j < 4; j++) {
            int n = n0 + wn + j * 16 + l15;
#pragma unroll
            for (int rr = 0; rr < 4; rr++)
                C[(size_t)(m + rr) * N + n] = (__bf16)acc[i][j][rr];
        }
    }
}

// ---------------- persistent bidirectional LSTM layer ----------------
// grid = 128 blocks: [bg(4)][dir(2)][nb(16)], 256 threads.
// Block: batch rows m0..m0+15, h/c cols j0..j0+31 (N-slice of 128 gate cols).
// U slice held in registers; h exchanged via double-buffered global h_buf.
__global__ __launch_bounds__(256, 1) void lstm_layer(
    const __bf16* __restrict__ xz_f, const __bf16* __restrict__ xz_b,
    const float* __restrict__ bias2, const __bf16* __restrict__ Ut2,
    const float* __restrict__ h0, const float* __restrict__ c0,
    __bf16* __restrict__ out, int last_only,
    float* __restrict__ fh, float* __restrict__ fc,
    __bf16* __restrict__ h_buf, int* __restrict__ counters) {
    const int tid = threadIdx.x;
    const int lane = tid & 63, w = tid >> 6;       // w = gate index (i,f,g,o)
    const int l15 = lane & 15, quad = lane >> 4;
    const int bid = blockIdx.x;
    const int nb = bid & 15, d = (bid >> 4) & 1, bg = bid >> 5;
    const int gid = bid >> 4;                      // sync group 0..7
    const int j0 = nb * 32;
    const int m0 = bg * 16;
    int* cnt = counters + gid * (T_SEQ + 1);

    const __bf16* Ut = Ut2 + (size_t)d * 2048 * HH;
    const float* bias = bias2 + d * 2048;
    const __bf16* xzd = d ? xz_b : xz_f;

    // U fragments: wave w holds gate w, cols j0..j0+31 as 2 MFMA n-tiles
    bf16x8 uf[2][16];
#pragma unroll
    for (int tt = 0; tt < 2; tt++) {
        const __bf16* up = Ut + (size_t)(w * 512 + j0 + tt * 16 + l15) * HH + quad * 8;
#pragma unroll
        for (int kk = 0; kk < 16; kk++)
            uf[tt][kk] = *(const bf16x8*)(up + kk * 32);
    }
    float bz[2];
#pragma unroll
    for (int tt = 0; tt < 2; tt++)
        bz[tt] = bias[w * 512 + j0 + tt * 16 + l15];

    // per-thread cell state: m = tid>>4, cols cj, cj+1
    const int cm = tid >> 4;
    const int cj = (tid & 15) * 2;
    const int cb = m0 + cm;
    float creg[2], hv[2];
#pragma unroll
    for (int q = 0; q < 2; q++) {
        creg[q] = c0[((size_t)d * BB + cb) * HH + j0 + cj + q];
        hv[q] = h0[((size_t)d * BB + cb) * HH + j0 + cj + q];
    }

    __shared__ float z_lds[4][16][32];

    // publish phase 0 (initial h)
    {
        bf16x2 hp; hp[0] = (__bf16)hv[0]; hp[1] = (__bf16)hv[1];
        *(bf16x2*)(h_buf + ((size_t)(0 * 2 + d) * BB + cb) * HH + j0 + cj) = hp;
    }
    __builtin_amdgcn_fence(__ATOMIC_RELEASE, "agent");
    __syncthreads();
    if (tid == 0) __hip_atomic_fetch_add(&cnt[0], 1, __ATOMIC_RELEASE, __HIP_MEMORY_SCOPE_AGENT);

    for (int t = 0; t < T_SEQ; t++) {
        const int tx = d ? (T_SEQ - 1 - t) : t;
        // prefetch xz into regs (overlaps with spin wait)
        float xv[2][4];
        {
            const __bf16* xp = xzd + ((size_t)tx * BB + m0 + quad * 4) * 2048 + w * 512 + j0 + l15;
#pragma unroll
            for (int tt = 0; tt < 2; tt++)
#pragma unroll
                for (int rr = 0; rr < 4; rr++)
                    xv[tt][rr] = (float)xp[(size_t)rr * 2048 + tt * 16];
        }
        // wait for phase t from the 16 blocks of this group
        if (tid == 0) {
            int it = 0;
            while (__hip_atomic_load(&cnt[t], __ATOMIC_RELAXED, __HIP_MEMORY_SCOPE_AGENT) < 16) {
                __builtin_amdgcn_s_sleep(2);
                if (++it > (1 << 22)) break; // safety against deadlock-hang
            }
        }
        __syncthreads();
        __builtin_amdgcn_fence(__ATOMIC_ACQUIRE, "agent");

        // load h fragments (A operand): rows = batch, k over H
        const __bf16* hp = h_buf + ((size_t)((t & 1) * 2 + d) * BB + m0 + l15) * HH + quad * 8;
        bf16x8 af[16];
#pragma unroll
        for (int kk = 0; kk < 16; kk++)
            af[kk] = *(const bf16x8*)(hp + kk * 32);
        f32x4 acc[2] = {};
#pragma unroll
        for (int kk = 0; kk < 16; kk++) {
            acc[0] = __builtin_amdgcn_mfma_f32_16x16x32_bf16(af[kk], uf[0][kk], acc[0], 0, 0, 0);
            acc[1] = __builtin_amdgcn_mfma_f32_16x16x32_bf16(af[kk], uf[1][kk], acc[1], 0, 0, 0);
        }
#pragma unroll
        for (int tt = 0; tt < 2; tt++)
#pragma unroll
            for (int rr = 0; rr < 4; rr++)
                z_lds[w][quad * 4 + rr][tt * 16 + l15] = acc[tt][rr] + xv[tt][rr] + bz[tt];
        __syncthreads();

        // gate combine (Keras order i,f,g,o)
#pragma unroll
        for (int q = 0; q < 2; q++) {
            float iv = z_lds[0][cm][cj + q];
            float fv = z_lds[1][cm][cj + q];
            float gv = z_lds[2][cm][cj + q];
            float ov = z_lds[3][cm][cj + q];
            float c = sigmoidf_(fv) * creg[q] + sigmoidf_(iv) * tanhf_(gv);
            creg[q] = c;
            hv[q] = sigmoidf_(ov) * tanhf_(c);
        }
        bf16x2 hp2; hp2[0] = (__bf16)hv[0]; hp2[1] = (__bf16)hv[1];
        *(bf16x2*)(h_buf + ((size_t)(((t + 1) & 1) * 2 + d) * BB + cb) * HH + j0 + cj) = hp2;
        if (out) {
            if (!last_only)
                *(bf16x2*)(out + ((size_t)tx * BB + cb) * 1024 + d * 512 + j0 + cj) = hp2;
            else if (tx == T_SEQ - 1)
                *(bf16x2*)(out + (size_t)cb * 1024 + d * 512 + j0 + cj) = hp2;
        }
        if (t == T_SEQ - 1) {
#pragma unroll
            for (int q = 0; q < 2; q++) {
                fh[((size_t)d * BB + cb) * HH + j0 + cj + q] = hv[q];
                fc[((size_t)d * BB + cb) * HH + j0 + cj + q] = creg[q];
            }
        }
        __builtin_amdgcn_fence(__ATOMIC_RELEASE, "agent");
        __syncthreads();
        if (tid == 0) __hip_atomic_fetch_add(&cnt[t + 1], 1, __ATOMIC_RELEASE, __HIP_MEMORY_SCOPE_AGENT);
    }
}

// ---------------- final dense: out[64,32000] = h_last[64,1024] @ W + b ------
// h_last: bf16 [64][1024]
__global__ __launch_bounds__(256) void dense_out(const __bf16* __restrict__ hlast,
                                                 const float* __restrict__ Wd,
                                                 const float* __restrict__ bv,
                                                 float* __restrict__ outp) {
    const int n = blockIdx.x * 256 + threadIdx.x; // 0..31999
    const int bh = blockIdx.y * 32;
    __shared__ __align__(16) __bf16 hl[32][1024]; // 64KB
    for (int e = threadIdx.x; e < 32 * 1024; e += 256) {
        int b = e >> 10, k = e & 1023;
        hl[b][k] = hlast[(size_t)(bh + b) * 1024 + k];
    }
    __syncthreads();
    float acc[32] = {};
    for (int kb = 0; kb < 128; kb++) {
        float wv[8];
#pragma unroll
        for (int j = 0; j < 8; j++) wv[j] = Wd[(size_t)(kb * 8 + j) * 32000 + n];
#pragma unroll
        for (int b = 0; b < 32; b++) {
            bf16x8 hv8 = *(const bf16x8*)(&hl[b][kb * 8]);
#pragma unroll
            for (int j = 0; j < 8; j++) acc[b] += (float)hv8[j] * wv[j];
        }
    }
#pragma unroll
    for (int b = 0; b < 32; b++)
        outp[(size_t)(bh + b) * 32000 + n] = acc[b] + bv[n];
}

extern "C" void kernel_launch(void* const* d_in, const int* in_sizes, int n_in,
                              void* d_out, int out_size, void* d_ws, size_t ws_size,
                              hipStream_t stream) {
    const int* enc_tok = (const int*)d_in[0];
    const int* dec_tok = (const int*)d_in[1];
    const float* emb = (const float*)d_in[2];
    const float* W_in = (const float*)d_in[3];
    const float* W_hid = (const float*)d_in[4];
    const float* U_all = (const float*)d_in[5];
    const float* b_all = (const float*)d_in[6];
    const float* dense_W = (const float*)d_in[7];
    const float* dense_b = (const float*)d_in[8];
    float* outp = (float*)d_out;

    char* p = (char*)d_ws;
    auto alloc = [&](size_t bytes) {
        char* r = p;
        p += (bytes + 255) & ~(size_t)255;
        return r;
    };
    float* zeros = (float*)alloc(2 * 64 * 512 * 4);       // zero h0/c0
    int* counters = (int*)alloc(4 * 8 * 257 * 4);
    size_t zlen = (size_t)(p - (char*)d_ws);
    hipMemsetAsync(d_ws, 0, zlen, stream);

    float* fh = (float*)alloc((size_t)4 * 2 * 64 * 512 * 4);
    float* fc = (float*)alloc((size_t)4 * 2 * 64 * 512 * 4);
    __bf16* h_buf = (__bf16*)alloc((size_t)2 * 2 * 64 * 512 * 2);
    __bf16* Ut = (__bf16*)alloc((size_t)4 * 2 * 2048 * 512 * 2);
    __bf16* Wt_in = (__bf16*)alloc((size_t)2 * 2 * 2048 * 512 * 2);
    __bf16* Wt_hid = (__bf16*)alloc((size_t)2 * 2 * 2048 * 1024 * 2);
    __bf16* x_buf = (__bf16*)alloc((size_t)256 * 64 * 512 * 2);     // shared enc/dec gather
    __bf16* seq_buf = (__bf16*)alloc((size_t)256 * 64 * 1024 * 2);  // out_e0, later out_d0
    __bf16* h_last = (__bf16*)alloc((size_t)64 * 1024 * 2);         // dec1 last-step output
    __bf16* xzf = (__bf16*)alloc((size_t)256 * 64 * 2048 * 2);
    __bf16* xzb = (__bf16*)alloc((size_t)256 * 64 * 2048 * 2);

    transpose_w<<<dim3(32, 8, 8), 256, 0, stream>>>(U_all, Ut, 512, 2048);
    transpose_w<<<dim3(32, 8, 4), 256, 0, stream>>>(W_in, Wt_in, 512, 2048);
    transpose_w<<<dim3(32, 16, 4), 256, 0, stream>>>(W_hid, Wt_hid, 1024, 2048);

    const __bf16* Wt_in_d = Wt_in + (size_t)2 * 2048 * 512;
    const __bf16* Wt_hid_d = Wt_hid + (size_t)2 * 2048 * 1024;
    size_t ws512 = (size_t)2048 * 512, ws1024 = (size_t)2048 * 1024;

    // ---- encoder layer 0 ----
    gather_emb<<<32768, 256, 0, stream>>>(enc_tok, emb, x_buf, 256);
    gemm_bf16<<<dim3(16, 128), 256, 0, stream>>>(x_buf, Wt_in, xzf, 16384, 2048, 512);
    gemm_bf16<<<dim3(16, 128), 256, 0, stream>>>(x_buf, Wt_in + ws512, xzb, 16384, 2048, 512);
    lstm_layer<<<128, 256, 0, stream>>>(xzf, xzb, b_all, Ut, zeros, zeros,
                                        seq_buf, 0, fh, fc, h_buf, counters);
    // ---- encoder layer 1 ----
    gemm_bf16<<<dim3(16, 128), 256, 0, stream>>>(seq_buf, Wt_hid, xzf, 16384, 2048, 1024);
    gemm_bf16<<<dim3(16, 128), 256, 0, stream>>>(seq_buf, Wt_hid + ws1024, xzb, 16384, 2048, 1024);
    // dec gather can start now (x_buf's enc contents consumed above)
    gather_emb<<<32768, 256, 0, stream>>>(dec_tok, emb, x_buf, 256);
    lstm_layer<<<128, 256, 0, stream>>>(xzf, xzb, b_all + (size_t)1 * 2 * 2048,
                                        Ut + (size_t)1 * 2 * 2048 * 512, fh, fc,
                                        nullptr, 0, fh + 65536, fc + 65536, h_buf,
                                        counters + 1 * 8 * 257);
    // ---- decoder layer 0 (init from encoder final states) ----
    gemm_bf16<<<dim3(16, 128), 256, 0, stream>>>(x_buf, Wt_in_d, xzf, 16384, 2048, 512);
    gemm_bf16<<<dim3(16, 128), 256, 0, stream>>>(x_buf, Wt_in_d + ws512, xzb, 16384, 2048, 512);
    lstm_layer<<<128, 256, 0, stream>>>(xzf, xzb, b_all + (size_t)2 * 2 * 2048,
                                        Ut + (size_t)2 * 2 * 2048 * 512,
                                        fh + 65536, fc + 65536,
                                        seq_buf, 0, fh + 2 * 65536, fc + 2 * 65536, h_buf,
                                        counters + 2 * 8 * 257);
    // ---- decoder layer 1 ----
    gemm_bf16<<<dim3(16, 128), 256, 0, stream>>>(seq_buf, Wt_hid_d, xzf, 16384, 2048, 1024);
    gemm_bf16<<<dim3(16, 128), 256, 0, stream>>>(seq_buf, Wt_hid_d + ws1024, xzb, 16384, 2048, 1024);
    lstm_layer<<<128, 256, 0, stream>>>(xzf, xzb, b_all + (size_t)3 * 2 * 2048,
                                        Ut + (size_t)3 * 2 * 2048 * 512,
                                        fh + 2 * 65536, fc + 2 * 65536,
                                        h_last, 1, fh + 3 * 65536, fc + 3 * 65536, h_buf,
                                        counters + 3 * 8 * 257);
    // ---- dense head ----
    dense_out<<<dim3(125, 2), 256, 0, stream>>>(h_last, dense_W, dense_b, outp);
}

// Round 3
// 6847.283 us; speedup vs baseline: 2.6289x; 2.6289x over previous
//
#include <hip/hip_runtime.h>

typedef __bf16 bf16x8 __attribute__((ext_vector_type(8)));
typedef __bf16 bf16x2 __attribute__((ext_vector_type(2)));
typedef float f32x4 __attribute__((ext_vector_type(4)));

#define T_SEQ 256
#define BB 64
#define HH 512

__device__ __forceinline__ float sigmoidf_(float x) {
    return 1.f / (1.f + __expf(-x));
}
__device__ __forceinline__ float tanhf_(float x) {
    return 1.f - 2.f / (__expf(2.f * x) + 1.f);
}

// ---------------- gather embeddings -> bf16 [T][B][H] ----------------
__global__ void gather_emb(const int* __restrict__ tok, const float* __restrict__ emb,
                           __bf16* __restrict__ x, int T) {
    size_t e = (size_t)blockIdx.x * blockDim.x + threadIdx.x; // over T*64*512
    int h = (int)(e & 511);
    int b = (int)((e >> 9) & 63);
    int t = (int)(e >> 15);
    int tk = tok[b * T + t];
    x[e] = (__bf16)emb[(size_t)tk * 512 + h];
}

// ---------------- transpose+convert f32 [R][C] -> bf16 [C][R], batched in z ----
__global__ void transpose_w(const float* __restrict__ in, __bf16* __restrict__ out,
                            int R, int C) {
    __shared__ __bf16 tile[64][66];
    const size_t sl = (size_t)blockIdx.z * R * C;
    in += sl; out += sl;
    int c0 = blockIdx.x * 64, r0 = blockIdx.y * 64;
    int ci = threadIdx.x & 63, rb = threadIdx.x >> 6;
#pragma unroll
    for (int s = 0; s < 16; s++) {
        int ri = s * 4 + rb;
        tile[ri][ci] = (__bf16)in[(size_t)(r0 + ri) * C + c0 + ci];
    }
    __syncthreads();
#pragma unroll
    for (int s = 0; s < 16; s++) {
        int cc = s * 4 + rb;
        out[(size_t)(c0 + cc) * R + r0 + ci] = tile[ci][cc];
    }
}

// ---------------- bf16 MFMA GEMM: C[M,N](bf16) = A[M,K] @ Bt[N,K]^T ----------
__global__ __launch_bounds__(256) void gemm_bf16(const __bf16* __restrict__ A,
                                                 const __bf16* __restrict__ Bt,
                                                 __bf16* __restrict__ C,
                                                 int M, int N, int K) {
    __shared__ __align__(16) __bf16 As[128 * 32];
    __shared__ __align__(16) __bf16 Bs[128 * 32];
    const int tid = threadIdx.x;
    const int lane = tid & 63, w = tid >> 6;
    const int l15 = lane & 15, quad = lane >> 4;
    const int m0 = blockIdx.y * 128, n0 = blockIdx.x * 128;
    const int wm = (w >> 1) * 64, wn = (w & 1) * 64;
    f32x4 acc[4][4] = {};
    const int r = tid >> 1, seg = (tid & 1) * 16;
    const __bf16* Ag = A + (size_t)(m0 + r) * K + seg;
    const __bf16* Bg = Bt + (size_t)(n0 + r) * K + seg;
    for (int kb = 0; kb < K; kb += 32) {
        // each thread stages 16 bf16 = 32 bytes (two uint4 copies)
        *(uint4*)(&As[r * 32 + seg]) = *(const uint4*)(Ag + kb);
        *(uint4*)(&As[r * 32 + seg + 8]) = *(const uint4*)(Ag + kb + 8);
        *(uint4*)(&Bs[r * 32 + seg]) = *(const uint4*)(Bg + kb);
        *(uint4*)(&Bs[r * 32 + seg + 8]) = *(const uint4*)(Bg + kb + 8);
        __syncthreads();
        bf16x8 fa[4], fb[4];
#pragma unroll
        for (int i = 0; i < 4; i++)
            fa[i] = *(const bf16x8*)(&As[(wm + i * 16 + l15) * 32 + quad * 8]);
#pragma unroll
        for (int j = 0; j < 4; j++)
            fb[j] = *(const bf16x8*)(&Bs[(wn + j * 16 + l15) * 32 + quad * 8]);
#pragma unroll
        for (int i = 0; i < 4; i++)
#pragma unroll
            for (int j = 0; j < 4; j++)
                acc[i][j] = __builtin_amdgcn_mfma_f32_16x16x32_bf16(fa[i], fb[j], acc[i][j], 0, 0, 0);
        __syncthreads();
    }
#pragma unroll
    for (int i = 0; i < 4; i++) {
        int m = m0 + wm + i * 16 + quad * 4;
#pragma unroll
        for (int j = 0; j < 4; j++) {
            int n = n0 + wn + j * 16 + l15;
#pragma unroll
            for (int rr = 0; rr < 4; rr++)
                C[(size_t)(m + rr) * N + n] = (__bf16)acc[i][j][rr];
        }
    }
}

// ---------------- persistent bidirectional LSTM layer ----------------
// grid = 128 blocks: [bg(4)][dir(2)][nb(16)], 256 threads.
// Block: batch rows m0..m0+15, h/c cols j0..j0+31 (N-slice of 128 gate cols).
// h exchanged via double-buffered global h_buf using RELAXED agent-scope
// atomics (sc0/sc1 cache-bypass per access). NO fences in the loop — agent
// release/acquire fences emit buffer_wbl2/buffer_inv (full per-XCD L2
// writeback+invalidate per step) which was the 16.8us/step bottleneck.
__global__ __launch_bounds__(256, 1) void lstm_layer(
    const __bf16* __restrict__ xz_f, const __bf16* __restrict__ xz_b,
    const float* __restrict__ bias2, const __bf16* __restrict__ Ut2,
    const float* __restrict__ h0, const float* __restrict__ c0,
    __bf16* __restrict__ out, int last_only,
    float* __restrict__ fh, float* __restrict__ fc,
    __bf16* __restrict__ h_buf, int* __restrict__ counters) {
    const int tid = threadIdx.x;
    const int lane = tid & 63, w = tid >> 6;       // w = gate index (i,f,g,o)
    const int l15 = lane & 15, quad = lane >> 4;
    const int bid = blockIdx.x;
    const int nb = bid & 15, d = (bid >> 4) & 1, bg = bid >> 5;
    const int gid = bid >> 4;                      // sync group 0..7
    const int j0 = nb * 32;
    const int m0 = bg * 16;
    int* cnt = counters + gid * (T_SEQ + 1);

    const __bf16* Ut = Ut2 + (size_t)d * 2048 * HH;
    const float* bias = bias2 + d * 2048;
    const __bf16* xzd = d ? xz_b : xz_f;

    // U fragments: wave w holds gate w, cols j0..j0+31 as 2 MFMA n-tiles.
    // (Compiler streams these from L2 each step; with no L2 invalidation the
    // 128KB/block slice stays L2-resident: 16 blocks/XCD * 128KB = 2MB < 4MB.)
    const __bf16* up0 = Ut + (size_t)(w * 512 + j0 + l15) * HH + quad * 8;
    const __bf16* up1 = Ut + (size_t)(w * 512 + j0 + 16 + l15) * HH + quad * 8;
    float bz[2];
#pragma unroll
    for (int tt = 0; tt < 2; tt++)
        bz[tt] = bias[w * 512 + j0 + tt * 16 + l15];

    // per-thread cell state: m = tid>>4, cols cj, cj+1
    const int cm = tid >> 4;
    const int cj = (tid & 15) * 2;
    const int cb = m0 + cm;
    float creg[2], hv[2];
#pragma unroll
    for (int q = 0; q < 2; q++) {
        creg[q] = c0[((size_t)d * BB + cb) * HH + j0 + cj + q];
        hv[q] = h0[((size_t)d * BB + cb) * HH + j0 + cj + q];
    }

    __shared__ float z_lds[4][16][32];

    typedef union { bf16x2 v; unsigned u; } B2U;
    typedef union { bf16x8 v; unsigned long long u[2]; } B8U;

    // publish phase 0 (initial h)
    {
        B2U hp; hp.v[0] = (__bf16)hv[0]; hp.v[1] = (__bf16)hv[1];
        __hip_atomic_store((unsigned*)(h_buf + ((size_t)(0 * 2 + d) * BB + cb) * HH + j0 + cj),
                           hp.u, __ATOMIC_RELAXED, __HIP_MEMORY_SCOPE_AGENT);
    }
    asm volatile("s_waitcnt vmcnt(0)" ::: "memory");
    __syncthreads();
    if (tid == 0) __hip_atomic_fetch_add(&cnt[0], 1, __ATOMIC_RELAXED, __HIP_MEMORY_SCOPE_AGENT);

    for (int t = 0; t < T_SEQ; t++) {
        const int tx = d ? (T_SEQ - 1 - t) : t;
        // prefetch xz into regs (overlaps with spin wait)
        float xv[2][4];
        {
            const __bf16* xp = xzd + ((size_t)tx * BB + m0 + quad * 4) * 2048 + w * 512 + j0 + l15;
#pragma unroll
            for (int tt = 0; tt < 2; tt++)
#pragma unroll
                for (int rr = 0; rr < 4; rr++)
                    xv[tt][rr] = (float)xp[(size_t)rr * 2048 + tt * 16];
        }
        // wait for phase t from the 16 blocks of this group
        if (tid == 0) {
            int it = 0;
            while (__hip_atomic_load(&cnt[t], __ATOMIC_RELAXED, __HIP_MEMORY_SCOPE_AGENT) < 16) {
                __builtin_amdgcn_s_sleep(1);
                if (++it > (1 << 22)) break; // safety against deadlock-hang
            }
        }
        __syncthreads();

        // load h fragments (A operand) via relaxed agent atomics (L1/L2 bypass)
        const __bf16* hp = h_buf + ((size_t)((t & 1) * 2 + d) * BB + m0 + l15) * HH + quad * 8;
        bf16x8 af[16];
#pragma unroll
        for (int kk = 0; kk < 16; kk++) {
            B8U u;
            u.u[0] = __hip_atomic_load((const unsigned long long*)(hp + kk * 32),
                                       __ATOMIC_RELAXED, __HIP_MEMORY_SCOPE_AGENT);
            u.u[1] = __hip_atomic_load((const unsigned long long*)(hp + kk * 32 + 4),
                                       __ATOMIC_RELAXED, __HIP_MEMORY_SCOPE_AGENT);
            af[kk] = u.v;
        }
        f32x4 acc[2] = {};
#pragma unroll
        for (int kk = 0; kk < 16; kk++) {
            bf16x8 u0 = *(const bf16x8*)(up0 + kk * 32);
            bf16x8 u1 = *(const bf16x8*)(up1 + kk * 32);
            acc[0] = __builtin_amdgcn_mfma_f32_16x16x32_bf16(af[kk], u0, acc[0], 0, 0, 0);
            acc[1] = __builtin_amdgcn_mfma_f32_16x16x32_bf16(af[kk], u1, acc[1], 0, 0, 0);
        }
#pragma unroll
        for (int tt = 0; tt < 2; tt++)
#pragma unroll
            for (int rr = 0; rr < 4; rr++)
                z_lds[w][quad * 4 + rr][tt * 16 + l15] = acc[tt][rr] + xv[tt][rr] + bz[tt];
        __syncthreads();

        // gate combine (Keras order i,f,g,o)
#pragma unroll
        for (int q = 0; q < 2; q++) {
            float iv = z_lds[0][cm][cj + q];
            float fv = z_lds[1][cm][cj + q];
            float gv = z_lds[2][cm][cj + q];
            float ov = z_lds[3][cm][cj + q];
            float c = sigmoidf_(fv) * creg[q] + sigmoidf_(iv) * tanhf_(gv);
            creg[q] = c;
            hv[q] = sigmoidf_(ov) * tanhf_(c);
        }
        B2U hp2; hp2.v[0] = (__bf16)hv[0]; hp2.v[1] = (__bf16)hv[1];
        __hip_atomic_store((unsigned*)(h_buf + ((size_t)(((t + 1) & 1) * 2 + d) * BB + cb) * HH + j0 + cj),
                           hp2.u, __ATOMIC_RELAXED, __HIP_MEMORY_SCOPE_AGENT);
        if (out) {
            if (!last_only)
                *(bf16x2*)(out + ((size_t)tx * BB + cb) * 1024 + d * 512 + j0 + cj) = hp2.v;
            else if (tx == T_SEQ - 1)
                *(bf16x2*)(out + (size_t)cb * 1024 + d * 512 + j0 + cj) = hp2.v;
        }
        if (t == T_SEQ - 1) {
#pragma unroll
            for (int q = 0; q < 2; q++) {
                fh[((size_t)d * BB + cb) * HH + j0 + cj + q] = hv[q];
                fc[((size_t)d * BB + cb) * HH + j0 + cj + q] = creg[q];
            }
        }
        asm volatile("s_waitcnt vmcnt(0)" ::: "memory");
        __syncthreads();
        if (tid == 0) __hip_atomic_fetch_add(&cnt[t + 1], 1, __ATOMIC_RELAXED, __HIP_MEMORY_SCOPE_AGENT);
    }
}

// ---------------- final dense: out[64,32000] = h_last[64,1024] @ W + b ------
// h_last: bf16 [64][1024]
__global__ __launch_bounds__(256) void dense_out(const __bf16* __restrict__ hlast,
                                                 const float* __restrict__ Wd,
                                                 const float* __restrict__ bv,
                                                 float* __restrict__ outp) {
    const int n = blockIdx.x * 256 + threadIdx.x; // 0..31999
    const int bh = blockIdx.y * 32;
    __shared__ __align__(16) __bf16 hl[32][1024]; // 64KB
    for (int e = threadIdx.x; e < 32 * 1024; e += 256) {
        int b = e >> 10, k = e & 1023;
        hl[b][k] = hlast[(size_t)(bh + b) * 1024 + k];
    }
    __syncthreads();
    float acc[32] = {};
    for (int kb = 0; kb < 128; kb++) {
        float wv[8];
#pragma unroll
        for (int j = 0; j < 8; j++) wv[j] = Wd[(size_t)(kb * 8 + j) * 32000 + n];
#pragma unroll
        for (int b = 0; b < 32; b++) {
            bf16x8 hv8 = *(const bf16x8*)(&hl[b][kb * 8]);
#pragma unroll
            for (int j = 0; j < 8; j++) acc[b] += (float)hv8[j] * wv[j];
        }
    }
#pragma unroll
    for (int b = 0; b < 32; b++)
        outp[(size_t)(bh + b) * 32000 + n] = acc[b] + bv[n];
}

extern "C" void kernel_launch(void* const* d_in, const int* in_sizes, int n_in,
                              void* d_out, int out_size, void* d_ws, size_t ws_size,
                              hipStream_t stream) {
    const int* enc_tok = (const int*)d_in[0];
    const int* dec_tok = (const int*)d_in[1];
    const float* emb = (const float*)d_in[2];
    const float* W_in = (const float*)d_in[3];
    const float* W_hid = (const float*)d_in[4];
    const float* U_all = (const float*)d_in[5];
    const float* b_all = (const float*)d_in[6];
    const float* dense_W = (const float*)d_in[7];
    const float* dense_b = (const float*)d_in[8];
    float* outp = (float*)d_out;

    char* p = (char*)d_ws;
    auto alloc = [&](size_t bytes) {
        char* r = p;
        p += (bytes + 255) & ~(size_t)255;
        return r;
    };
    float* zeros = (float*)alloc(2 * 64 * 512 * 4);       // zero h0/c0
    int* counters = (int*)alloc(4 * 8 * 257 * 4);
    size_t zlen = (size_t)(p - (char*)d_ws);
    hipMemsetAsync(d_ws, 0, zlen, stream);

    float* fh = (float*)alloc((size_t)4 * 2 * 64 * 512 * 4);
    float* fc = (float*)alloc((size_t)4 * 2 * 64 * 512 * 4);
    __bf16* h_buf = (__bf16*)alloc((size_t)2 * 2 * 64 * 512 * 2);
    __bf16* Ut = (__bf16*)alloc((size_t)4 * 2 * 2048 * 512 * 2);
    __bf16* Wt_in = (__bf16*)alloc((size_t)2 * 2 * 2048 * 512 * 2);
    __bf16* Wt_hid = (__bf16*)alloc((size_t)2 * 2 * 2048 * 1024 * 2);
    __bf16* x_buf = (__bf16*)alloc((size_t)256 * 64 * 512 * 2);     // shared enc/dec gather
    __bf16* seq_buf = (__bf16*)alloc((size_t)256 * 64 * 1024 * 2);  // out_e0, later out_d0
    __bf16* h_last = (__bf16*)alloc((size_t)64 * 1024 * 2);         // dec1 last-step output
    __bf16* xzf = (__bf16*)alloc((size_t)256 * 64 * 2048 * 2);
    __bf16* xzb = (__bf16*)alloc((size_t)256 * 64 * 2048 * 2);

    transpose_w<<<dim3(32, 8, 8), 256, 0, stream>>>(U_all, Ut, 512, 2048);
    transpose_w<<<dim3(32, 8, 4), 256, 0, stream>>>(W_in, Wt_in, 512, 2048);
    transpose_w<<<dim3(32, 16, 4), 256, 0, stream>>>(W_hid, Wt_hid, 1024, 2048);

    const __bf16* Wt_in_d = Wt_in + (size_t)2 * 2048 * 512;
    const __bf16* Wt_hid_d = Wt_hid + (size_t)2 * 2048 * 1024;
    size_t ws512 = (size_t)2048 * 512, ws1024 = (size_t)2048 * 1024;

    // ---- encoder layer 0 ----
    gather_emb<<<32768, 256, 0, stream>>>(enc_tok, emb, x_buf, 256);
    gemm_bf16<<<dim3(16, 128), 256, 0, stream>>>(x_buf, Wt_in, xzf, 16384, 2048, 512);
    gemm_bf16<<<dim3(16, 128), 256, 0, stream>>>(x_buf, Wt_in + ws512, xzb, 16384, 2048, 512);
    lstm_layer<<<128, 256, 0, stream>>>(xzf, xzb, b_all, Ut, zeros, zeros,
                                        seq_buf, 0, fh, fc, h_buf, counters);
    // ---- encoder layer 1 ----
    gemm_bf16<<<dim3(16, 128), 256, 0, stream>>>(seq_buf, Wt_hid, xzf, 16384, 2048, 1024);
    gemm_bf16<<<dim3(16, 128), 256, 0, stream>>>(seq_buf, Wt_hid + ws1024, xzb, 16384, 2048, 1024);
    // dec gather can start now (x_buf's enc contents consumed above)
    gather_emb<<<32768, 256, 0, stream>>>(dec_tok, emb, x_buf, 256);
    lstm_layer<<<128, 256, 0, stream>>>(xzf, xzb, b_all + (size_t)1 * 2 * 2048,
                                        Ut + (size_t)1 * 2 * 2048 * 512, fh, fc,
                                        nullptr, 0, fh + 65536, fc + 65536, h_buf,
                                        counters + 1 * 8 * 257);
    // ---- decoder layer 0 (init from encoder final states) ----
    gemm_bf16<<<dim3(16, 128), 256, 0, stream>>>(x_buf, Wt_in_d, xzf, 16384, 2048, 512);
    gemm_bf16<<<dim3(16, 128), 256, 0, stream>>>(x_buf, Wt_in_d + ws512, xzb, 16384, 2048, 512);
    lstm_layer<<<128, 256, 0, stream>>>(xzf, xzb, b_all + (size_t)2 * 2 * 2048,
                                        Ut + (size_t)2 * 2 * 2048 * 512,
                                        fh + 65536, fc + 65536,
                                        seq_buf, 0, fh + 2 * 65536, fc + 2 * 65536, h_buf,
                                        counters + 2 * 8 * 257);
    // ---- decoder layer 1 ----
    gemm_bf16<<<dim3(16, 128), 256, 0, stream>>>(seq_buf, Wt_hid_d, xzf, 16384, 2048, 1024);
    gemm_bf16<<<dim3(16, 128), 256, 0, stream>>>(seq_buf, Wt_hid_d + ws1024, xzb, 16384, 2048, 1024);
    lstm_layer<<<128, 256, 0, stream>>>(xzf, xzb, b_all + (size_t)3 * 2 * 2048,
                                        Ut + (size_t)3 * 2 * 2048 * 512,
                                        fh + 2 * 65536, fc + 2 * 65536,
                                        h_last, 1, fh + 3 * 65536, fc + 3 * 65536, h_buf,
                                        counters + 3 * 8 * 257);
    // ---- dense head ----
    dense_out<<<dim3(125, 2), 256, 0, stream>>>(h_last, dense_W, dense_b, outp);
}